// Round 3
// baseline (4804.148 us; speedup 1.0000x reference)
//
#include <hip/hip_runtime.h>

// ResidualVQ on MI355X (gfx950). ROUND 3: bit-exact numpy fp32 replication.
// z: [65536, 256] f32; codebooks: [4, 1024, 256] f32.
// Outputs (flat f32 in d_out): z_q [65536*256], codes-as-float [65536*4], loss [1].
//
// R1/R2 both emitted the true fp64 argmin and both failed codes at absmax=836
// => np reference is fp32; flips occur where fp32 rounding noise (~ULP(256)=3e-5
// at the final (r2-2E)+c2 roundings) exceeds the true top-2 gap.
// This round replicates numpy's exact fp32 arithmetic:
//   E: einsum noblas SSE path - 4 accumulators (d mod 4), mul/add separately
//      rounded (NO FMA), hsum tree (e0+e1)+(e2+e3).
//   r2/c2: np.sum pairwise - two 128-blocks, 8 accumulators stride-8,
//      ((r0+r1)+(r2+r3))+((r4+r5)+(r6+r7)), then block0+block1.
//   dists = fl(fl(r2 - fl(2*E)) + c2); argmin first-min; residual fp32 subs.
// Fast FMA screen finds top-2 (values+indices); rows with screen-gap <
// 1.75e-4 (~90 sites/262k) get both candidates re-evaluated bit-exactly.

#define NB 65536
#define ND 256
#define NK 1024
#define NL 4
#define MROWS 64
#define KC 64
#define NCHUNK (NK / KC)
#define STRIDE 260          // padded LDS row stride (words); d=0..255 contiguous
#define FLAG_MARGIN 1.75e-4f

__device__ inline float dot4(float4 a, float4 b, float acc) {
  acc = fmaf(a.x, b.x, acc);
  acc = fmaf(a.y, b.y, acc);
  acc = fmaf(a.z, b.z, acc);
  acc = fmaf(a.w, b.w, acc);
  return acc;
}

// numpy np.sum(x*x) for 256 contiguous fp32: pairwise, PW_BLOCKSIZE=128.
__device__ float np_sum256_sq(const float* __restrict__ a) {
#pragma clang fp contract(off)
  float out[2];
  for (int h = 0; h < 2; ++h) {
    const float* p = a + 128 * h;
    float r[8];
    for (int j = 0; j < 8; ++j) r[j] = p[j] * p[j];
    for (int i = 8; i < 128; i += 8)
      for (int j = 0; j < 8; ++j) r[j] += p[i + j] * p[i + j];
    out[h] = ((r[0] + r[1]) + (r[2] + r[3])) + ((r[4] + r[5]) + (r[6] + r[7]));
  }
  return out[0] + out[1];
}

// numpy einsum 'bd,kd->bk' noblas SSE inner loop: 4 lane-accumulators
// (d mod 4, ascending d), separate mul/add roundings, hadd tree.
__device__ float np_einsum256(const float* __restrict__ r,
                              const float* __restrict__ c) {
#pragma clang fp contract(off)
  float e[4] = {0.f, 0.f, 0.f, 0.f};
  for (int d = 0; d < 256; d += 4) {
    e[0] += r[d + 0] * c[d + 0];
    e[1] += r[d + 1] * c[d + 1];
    e[2] += r[d + 2] * c[d + 2];
    e[3] += r[d + 3] * c[d + 3];
  }
  return (e[0] + e[1]) + (e[2] + e[3]);
}

__device__ float np_dist(const float* __restrict__ resrow,
                         const float* __restrict__ crow, float r2) {
#pragma clang fp contract(off)
  float E = np_einsum256(resrow, crow);
  float c2 = np_sum256_sq(crow);
  float t1 = r2 - 2.0f * E;
  return t1 + c2;
}

__global__ __launch_bounds__(256, 1)
void rvq_kernel(const float* __restrict__ z, const float* __restrict__ cb,
                float* __restrict__ out) {
  extern __shared__ char smem_raw[];
  float* res = (float*)smem_raw;                 // [MROWS][STRIDE]
  float* cbs = res + MROWS * STRIDE;             // [KC][STRIDE]
  int* selhist = (int*)(cbs + KC * STRIDE);      // [MROWS][NL]
  int* flags = selhist + MROWS * NL;             // [MROWS]
  int* cand2 = flags + MROWS;                    // [MROWS]
  // overlays on cbs (dead between compute phases):
  float* redm1 = cbs;                            // [MROWS][16]
  float* redm2 = redm1 + MROWS * 16;             // [MROWS][16]
  int*   redi1 = (int*)(redm2 + MROWS * 16);     // [MROWS][16]
  int*   redi2 = redi1 + MROWS * 16;             // [MROWS][16]
  double* redd = (double*)cbs;                   // [256] (loss, after levels)

  const int tid = threadIdx.x;
  const int row0 = blockIdx.x * MROWS;
  const int tx = tid & 15;   // code-group
  const int ty = tid >> 4;   // row-group

  // ---- stage residual = z (coalesced float4) ----
  for (int t = 0; t < 16; ++t) {
    int li = t * 256 + tid;
    int r = li >> 6, dv = li & 63;
    float4 v = ((const float4*)z)[(size_t)(row0 + r) * 64 + dv];
    *(float4*)&res[r * STRIDE + dv * 4] = v;
  }
  __syncthreads();

  for (int lvl = 0; lvl < NL; ++lvl) {
    // per-thread running top-2 (values + indices) for rows ty+16j
    float m1[4], m2[4]; int i1[4], i2[4];
#pragma unroll
    for (int j = 0; j < 4; ++j) { m1[j] = 1e30f; m2[j] = 1e30f; i1[j] = 0; i2[j] = 0; }

    for (int ch = 0; ch < NCHUNK; ++ch) {
      for (int t = 0; t < 16; ++t) {
        int li = t * 256 + tid;
        int c = li >> 6, dv = li & 63;
        float4 v = ((const float4*)cb)[(size_t)(lvl * NK + ch * KC + c) * 64 + dv];
        *(float4*)&cbs[c * STRIDE + dv * 4] = v;
      }
      __syncthreads();

      float acc[4][4] = {{0.f, 0.f, 0.f, 0.f}, {0.f, 0.f, 0.f, 0.f},
                         {0.f, 0.f, 0.f, 0.f}, {0.f, 0.f, 0.f, 0.f}};
      float accC[4] = {0.f, 0.f, 0.f, 0.f};
      const float* rp[4]; const float* cp[4];
#pragma unroll
      for (int j = 0; j < 4; ++j) rp[j] = res + (ty + 16 * j) * STRIDE;
#pragma unroll
      for (int q = 0; q < 4; ++q) cp[q] = cbs + (tx + 16 * q) * STRIDE;

      for (int d4 = 0; d4 < 64; ++d4) {
        float4 rv[4], cv[4];
#pragma unroll
        for (int j = 0; j < 4; ++j) rv[j] = *(const float4*)(rp[j] + d4 * 4);
#pragma unroll
        for (int q = 0; q < 4; ++q) cv[q] = *(const float4*)(cp[q] + d4 * 4);
#pragma unroll
        for (int q = 0; q < 4; ++q) {
          accC[q] = dot4(cv[q], cv[q], accC[q]);
#pragma unroll
          for (int j = 0; j < 4; ++j)
            acc[j][q] = dot4(rv[j], cv[q], acc[j][q]);
        }
      }

      // per-thread top-2 update (k ascending within thread: ch outer, q inner)
#pragma unroll
      for (int q = 0; q < 4; ++q) {
        const int k = ch * KC + tx + 16 * q;
#pragma unroll
        for (int j = 0; j < 4; ++j) {
          float dd = accC[q] - 2.0f * acc[j][q];
          if (dd < m1[j]) { m2[j] = m1[j]; i2[j] = i1[j]; m1[j] = dd; i1[j] = k; }
          else if (dd < m2[j]) { m2[j] = dd; i2[j] = k; }
        }
      }
      __syncthreads();
    }

    // ---- cross-thread top-2 merge (lex by (value, index)) ----
#pragma unroll
    for (int j = 0; j < 4; ++j) {
      int r = ty + 16 * j;
      redm1[r * 16 + tx] = m1[j];
      redm2[r * 16 + tx] = m2[j];
      redi1[r * 16 + tx] = i1[j];
      redi2[r * 16 + tx] = i2[j];
    }
    __syncthreads();
    if (tid < MROWS) {
      const int r = tid;
      float gm1 = 1e30f, gm2 = 1e30f; int gi1 = 0x7fffffff, gi2 = 0x7fffffff;
      for (int t = 0; t < 16; ++t) {
#pragma unroll
        for (int s = 0; s < 2; ++s) {
          float v = (s == 0) ? redm1[r * 16 + t] : redm2[r * 16 + t];
          int   i = (s == 0) ? redi1[r * 16 + t] : redi2[r * 16 + t];
          if (v < gm1 || (v == gm1 && i < gi1)) {
            gm2 = gm1; gi2 = gi1; gm1 = v; gi1 = i;
          } else if (v < gm2 || (v == gm2 && i < gi2)) {
            gm2 = v; gi2 = i;
          }
        }
      }
      selhist[r * NL + lvl] = gi1;
      cand2[r] = gi2;
      flags[r] = (gm2 - gm1 <= FLAG_MARGIN) ? 1 : 0;

      // ---- bit-exact numpy re-evaluation of near-tie rows (rare ~90/262k) ----
      if (flags[r]) {
        const float* resrow = res + r * STRIDE;   // d=0..255 contiguous
        float r2 = np_sum256_sq(resrow);
        int k1 = gi1, k2 = gi2;
        float d1 = np_dist(resrow, cb + (size_t)(lvl * NK + k1) * ND, r2);
        float d2 = np_dist(resrow, cb + (size_t)(lvl * NK + k2) * ND, r2);
        int w = (d2 < d1 || (d2 == d1 && k2 < k1)) ? k2 : k1;
        selhist[r * NL + lvl] = w;
      }
    }
    __syncthreads();

    // ---- residual update: res[i][d] -= cb[lvl][sel_i][d] (exact fp32 sub) ----
    for (int i = 0; i < MROWS; ++i) {
      const float* crow = cb + (size_t)(lvl * NK + selhist[i * NL + lvl]) * ND;
      res[i * STRIDE + tid] -= crow[tid];
    }
    __syncthreads();
  }

  // ---- epilogue: z_q = z - r_final, codes, loss ----
  double lacc = 0.0;
  for (int t = 0; t < 16; ++t) {
    int li = t * 256 + tid;
    int r = li >> 6, dv = li & 63;
    float4 zv = ((const float4*)z)[(size_t)(row0 + r) * 64 + dv];
    float4 rv = *(const float4*)&res[r * STRIDE + dv * 4];
    float4 o;
    o.x = zv.x - rv.x; o.y = zv.y - rv.y; o.z = zv.z - rv.z; o.w = zv.w - rv.w;
    ((float4*)out)[(size_t)(row0 + r) * 64 + dv] = o;
    lacc += (double)rv.x * rv.x + (double)rv.y * rv.y
          + (double)rv.z * rv.z + (double)rv.w * rv.w;
  }
  {
    int r = tid >> 2, l = tid & 3;
    out[(size_t)NB * ND + (size_t)(row0 + r) * NL + l] = (float)selhist[r * NL + l];
  }
  __syncthreads();  // cbs overlay (redd) reuse
  redd[tid] = lacc;
  __syncthreads();
  if (tid == 0) {
    double s = 0.0;
    for (int t = 0; t < 256; ++t) s += redd[t];
    atomicAdd(out + (size_t)NB * ND + (size_t)NB * NL,
              (float)(s / ((double)NB * (double)ND)));
  }
}

extern "C" void kernel_launch(void* const* d_in, const int* in_sizes, int n_in,
                              void* d_out, int out_size, void* d_ws, size_t ws_size,
                              hipStream_t stream) {
  const float* z  = (const float*)d_in[0];
  const float* cb = (const float*)d_in[1];
  float* out = (float*)d_out;

  hipMemsetAsync((void*)(out + (size_t)NB * ND + (size_t)NB * NL), 0,
                 sizeof(float), stream);

  const size_t shmem = (size_t)(MROWS * STRIDE + KC * STRIDE) * sizeof(float)
                     + (size_t)MROWS * NL * sizeof(int)
                     + (size_t)MROWS * sizeof(int) * 2;
  hipFuncSetAttribute((const void*)rvq_kernel,
                      hipFuncAttributeMaxDynamicSharedMemorySize, (int)shmem);

  rvq_kernel<<<dim3(NB / MROWS), dim3(256), shmem, stream>>>(z, cb, out);
}

// Round 4
// 1213.353 us; speedup vs baseline: 3.9594x; 3.9594x over previous
//
#include <hip/hip_runtime.h>

// ResidualVQ on MI355X (gfx950). ROUND 4: split-bf16 MFMA screen.
// z: [65536,256] f32; codebooks: [4,1024,256] f32.
// Outputs (flat f32): z_q [65536*256], codes-as-float [65536*4], loss [1].
//
// Screen: E = rhi*chi + rhi*clo + rlo*chi via mfma_f32_16x16x32_bf16 (3 passes);
// dist_s = c2[k] - 2E. Per-row top-2 -> flag if gap <= 1e-3 (~0.1% rows);
// flagged rows get full-K numpy-bit-exact rescan (R3-proven np_dist).
// Residual recomputed from z + selhist each level (fp32 subtract chain, exact).
// Prep kernels write cb_hi/cb_lo (bf16) + c2 (f32) into d_ws (needs ~4.2MB).

#define NB 65536
#define ND 256
#define NK 1024
#define NL 4
#define MROWS 128
#define NBLK (NB / MROWS)      // 512
#define CHUNK 64               // codes per LDS chunk
#define NCH (NK / CHUNK)       // 16
#define BSTR 264               // LDS B row stride in ushorts (512B + 16B pad -> balanced banks)
#define FLAG_MARGIN 1e-3f

typedef __attribute__((ext_vector_type(8))) short short8;
typedef __attribute__((ext_vector_type(4))) float f32x4;

__device__ inline unsigned short f2bf(float x) {
  unsigned u = __float_as_uint(x);
  u = u + 0x7FFFu + ((u >> 16) & 1u);        // RNE to bf16 (inputs are finite)
  return (unsigned short)(u >> 16);
}
__device__ inline float bf2f(unsigned short h) {
  return __uint_as_float(((unsigned)h) << 16);
}

// ---- numpy-bit-exact fp32 kernels (R3-proven) ----
__device__ float np_sum256_sq(const float* __restrict__ a) {
#pragma clang fp contract(off)
  float out[2];
  for (int h = 0; h < 2; ++h) {
    const float* p = a + 128 * h;
    float r[8];
    for (int j = 0; j < 8; ++j) r[j] = p[j] * p[j];
    for (int i = 8; i < 128; i += 8)
      for (int j = 0; j < 8; ++j) r[j] += p[i + j] * p[i + j];
    out[h] = ((r[0] + r[1]) + (r[2] + r[3])) + ((r[4] + r[5]) + (r[6] + r[7]));
  }
  return out[0] + out[1];
}
__device__ float np_einsum256(const float* __restrict__ r,
                              const float* __restrict__ c) {
#pragma clang fp contract(off)
  float e[4] = {0.f, 0.f, 0.f, 0.f};
  for (int d = 0; d < 256; d += 4) {
    e[0] += r[d + 0] * c[d + 0];
    e[1] += r[d + 1] * c[d + 1];
    e[2] += r[d + 2] * c[d + 2];
    e[3] += r[d + 3] * c[d + 3];
  }
  return (e[0] + e[1]) + (e[2] + e[3]);
}
__device__ float np_dist(const float* __restrict__ resrow,
                         const float* __restrict__ crow, float r2) {
#pragma clang fp contract(off)
  float E = np_einsum256(resrow, crow);
  float c2 = np_sum256_sq(crow);
  float t1 = r2 - 2.0f * E;
  return t1 + c2;
}

// ---- prep: split codebook into bf16 hi/lo, compute c2 ----
__global__ void prep_split(const float* __restrict__ cb,
                           unsigned short* __restrict__ whi,
                           unsigned short* __restrict__ wlo) {
  int i = blockIdx.x * 256 + threadIdx.x;   // 4096 blocks cover 1,048,576
  float c = cb[i];
  unsigned short h = f2bf(c);
  whi[i] = h;
  wlo[i] = f2bf(c - bf2f(h));
}
__global__ void prep_c2(const float* __restrict__ cb, float* __restrict__ c2) {
  int k = blockIdx.x;                        // 4096 codes total
  int lane = threadIdx.x;                    // 64
  const float* p = cb + (size_t)k * ND + lane * 4;
  double s = (double)p[0]*p[0] + (double)p[1]*p[1]
           + (double)p[2]*p[2] + (double)p[3]*p[3];
  for (int off = 32; off >= 1; off >>= 1) s += __shfl_down(s, off);
  if (lane == 0) c2[k] = (float)s;
}

// LDS map (74240 B):
//  bhi:   ushort[64*264]  @0       (33792)
//  blo:   ushort[64*264]  @33792   (33792)
//  c2s:   float[1024]     @67584   (4096)
//  selh:  int[128*4]      @71680   (2048)
//  flags: int[128]        @73728   (512)
// overlays inside bhi/blo (phase-disjoint, barrier-separated):
//  mscr:  float[128*16*4] @0       (32768)  merge dump
//  resr:  float[256]      @32768   (1024)
//  redf:  float[256]      @34816   (1024)
//  redk:  int[256]        @35840   (1024)
//  lred:  double[256]     @0       (2048)   loss reduction

__global__ __launch_bounds__(256, 2)
void rvq_main(const float* __restrict__ z, const float* __restrict__ cbf,
              const unsigned short* __restrict__ whi,
              const unsigned short* __restrict__ wlo,
              const float* __restrict__ c2w, float* __restrict__ out) {
  extern __shared__ char smem[];
  unsigned short* bhi = (unsigned short*)smem;
  unsigned short* blo = bhi + 64 * BSTR;
  float* c2s  = (float*)(smem + 67584);
  int*   selh = (int*)(smem + 71680);
  int*   flags= (int*)(smem + 73728);
  float* mscr = (float*)smem;
  float* resr = (float*)(smem + 32768);
  float* redf = (float*)(smem + 34816);
  int*   redk = (int*)(smem + 35840);
  double* lred= (double*)smem;

  const int tid  = threadIdx.x;
  const int wave = tid >> 6, lane = tid & 63;
  const int quad = lane >> 4, lx = lane & 15;
  const int blk  = blockIdx.x;

  for (int lvl = 0; lvl < NL; ++lvl) {
    __syncthreads();   // selh stable; c2s free to overwrite
    // ---- stage c2 for this level ----
#pragma unroll
    for (int t = 0; t < 4; ++t)
      c2s[t * 256 + tid] = c2w[lvl * NK + t * 256 + tid];

    // ---- build A-fragments (register-resident, 32 rows/wave) ----
    short8 Ah[2][8], Al[2][8];
#pragma unroll
    for (int s = 0; s < 2; ++s) {
      const int rloc = wave * 32 + s * 16 + lx;
      const size_t rg = (size_t)(blk * MROWS + rloc);
#pragma unroll
      for (int ks = 0; ks < 8; ++ks) {
        const int k0 = 32 * ks + quad * 8;
        const float* zp = z + rg * ND + k0;
        float4 p0 = *(const float4*)zp;
        float4 p1 = *(const float4*)(zp + 4);
        for (int l = 0; l < lvl; ++l) {
          int sel = selh[rloc * 4 + l];
          const float* cp = cbf + (size_t)(l * NK + sel) * ND + k0;
          float4 q0 = *(const float4*)cp, q1 = *(const float4*)(cp + 4);
          p0.x -= q0.x; p0.y -= q0.y; p0.z -= q0.z; p0.w -= q0.w;
          p1.x -= q1.x; p1.y -= q1.y; p1.z -= q1.z; p1.w -= q1.w;
        }
        float v0[8] = {p0.x, p0.y, p0.z, p0.w, p1.x, p1.y, p1.z, p1.w};
#pragma unroll
        for (int j = 0; j < 8; ++j) {
          unsigned short h = f2bf(v0[j]);
          Ah[s][ks][j] = (short)h;
          Al[s][ks][j] = (short)f2bf(v0[j] - bf2f(h));
        }
      }
    }

    // ---- screen: per-lane top-2 over 8 (stripe,reg) streams ----
    float m1[8], m2[8]; int i1[8];
#pragma unroll
    for (int t = 0; t < 8; ++t) { m1[t] = 1e30f; m2[t] = 1e30f; i1[t] = 0; }

#pragma unroll 1
    for (int ch = 0; ch < NCH; ++ch) {
      __syncthreads();   // bstage free (prev chunk's tiles done)
      {
        const size_t gb = (size_t)lvl * NK * ND + (size_t)ch * CHUNK * ND;
#pragma unroll
        for (int it = 0; it < 8; ++it) {
          int i = it * 256 + tid;           // 0..2047
          int code = i >> 5, col = i & 31;
          uint4 vh = *(const uint4*)(whi + gb + (size_t)code * ND + col * 8);
          *(uint4*)(bhi + code * BSTR + col * 8) = vh;
          uint4 vl = *(const uint4*)(wlo + gb + (size_t)code * ND + col * 8);
          *(uint4*)(blo + code * BSTR + col * 8) = vl;
        }
      }
      __syncthreads();
#pragma unroll 1
      for (int tile = 0; tile < 4; ++tile) {
        f32x4 a0a = {0,0,0,0}, a0b = {0,0,0,0}, a1a = {0,0,0,0}, a1b = {0,0,0,0};
        const int crow = tile * 16 + lx;
        const unsigned short* bph = bhi + crow * BSTR + quad * 8;
        const unsigned short* bpl = blo + crow * BSTR + quad * 8;
#pragma unroll
        for (int ks = 0; ks < 8; ks += 2) {
          short8 vb0 = *(const short8*)(bph + 32 * ks);
          short8 wb0 = *(const short8*)(bpl + 32 * ks);
          short8 vb1 = *(const short8*)(bph + 32 * ks + 32);
          short8 wb1 = *(const short8*)(bpl + 32 * ks + 32);
          a0a = __builtin_amdgcn_mfma_f32_16x16x32_bf16(Ah[0][ks], vb0, a0a, 0, 0, 0);
          a1a = __builtin_amdgcn_mfma_f32_16x16x32_bf16(Ah[1][ks], vb0, a1a, 0, 0, 0);
          a0a = __builtin_amdgcn_mfma_f32_16x16x32_bf16(Al[0][ks], vb0, a0a, 0, 0, 0);
          a1a = __builtin_amdgcn_mfma_f32_16x16x32_bf16(Al[1][ks], vb0, a1a, 0, 0, 0);
          a0a = __builtin_amdgcn_mfma_f32_16x16x32_bf16(Ah[0][ks], wb0, a0a, 0, 0, 0);
          a1a = __builtin_amdgcn_mfma_f32_16x16x32_bf16(Ah[1][ks], wb0, a1a, 0, 0, 0);
          a0b = __builtin_amdgcn_mfma_f32_16x16x32_bf16(Ah[0][ks + 1], vb1, a0b, 0, 0, 0);
          a1b = __builtin_amdgcn_mfma_f32_16x16x32_bf16(Ah[1][ks + 1], vb1, a1b, 0, 0, 0);
          a0b = __builtin_amdgcn_mfma_f32_16x16x32_bf16(Al[0][ks + 1], vb1, a0b, 0, 0, 0);
          a1b = __builtin_amdgcn_mfma_f32_16x16x32_bf16(Al[1][ks + 1], vb1, a1b, 0, 0, 0);
          a0b = __builtin_amdgcn_mfma_f32_16x16x32_bf16(Ah[0][ks + 1], wb1, a0b, 0, 0, 0);
          a1b = __builtin_amdgcn_mfma_f32_16x16x32_bf16(Ah[1][ks + 1], wb1, a1b, 0, 0, 0);
        }
        const int kidx = ch * CHUNK + crow;
        const float c2v = c2s[kidx];
#pragma unroll
        for (int s = 0; s < 2; ++s)
#pragma unroll
          for (int r = 0; r < 4; ++r) {
            float e = (s == 0) ? (a0a[r] + a0b[r]) : (a1a[r] + a1b[r]);
            float d = fmaf(-2.0f, e, c2v);
            int st = s * 4 + r;
            if (d < m1[st]) { m2[st] = m1[st]; m1[st] = d; i1[st] = kidx; }
            else if (d < m2[st]) m2[st] = d;
          }
      }
    }

    // ---- cross-lane top-2 merge (scratch overlays bstage) ----
    __syncthreads();
#pragma unroll
    for (int t = 0; t < 8; ++t) {
      int rloc = wave * 32 + (t >> 2) * 16 + quad * 4 + (t & 3);
      float* p = mscr + (rloc * 16 + lx) * 4;
      p[0] = m1[t]; p[1] = m2[t]; p[2] = __int_as_float(i1[t]);
    }
    __syncthreads();
    if (tid < MROWS) {
      float gm1 = 1e30f, gm2 = 1e30f; int gi1 = 0x7fffffff;
      for (int t = 0; t < 16; ++t) {
        const float* p = mscr + (tid * 16 + t) * 4;
        float a1 = p[0], a2 = p[1]; int ai = __float_as_int(p[2]);
        if (a1 < gm1 || (a1 == gm1 && ai < gi1)) {
          gm2 = fminf(gm1, a2); gm1 = a1; gi1 = ai;
        } else {
          gm2 = fminf(gm2, a1);
        }
      }
      selh[tid * 4 + lvl] = gi1;
      flags[tid] = (gm2 - gm1 <= FLAG_MARGIN) ? 1 : 0;
    }
    __syncthreads();

    // ---- numpy-bit-exact full-K rescan of flagged rows (~0.1%) ----
    for (int r = 0; r < MROWS; ++r) {
      if (flags[r]) {
        {
          float v = z[(size_t)(blk * MROWS + r) * ND + tid];
          for (int l = 0; l < lvl; ++l)
            v -= cbf[(size_t)(l * NK + selh[r * 4 + l]) * ND + tid];
          resr[tid] = v;
        }
        __syncthreads();
        float r2 = np_sum256_sq(resr);
        float bd = 1e30f; int bk = 0x7fffffff;
        for (int u = 0; u < 4; ++u) {
          int k = u * 256 + tid;
          float dd = np_dist(resr, cbf + (size_t)(lvl * NK + k) * ND, r2);
          if (dd < bd || (dd == bd && k < bk)) { bd = dd; bk = k; }
        }
        redf[tid] = bd; redk[tid] = bk;
        __syncthreads();
        if (tid == 0) {
          float gb = 1e30f; int gk = 0x7fffffff;
          for (int t2 = 0; t2 < 256; ++t2) {
            if (redf[t2] < gb || (redf[t2] == gb && redk[t2] < gk)) {
              gb = redf[t2]; gk = redk[t2];
            }
          }
          selh[r * 4 + lvl] = gk;
        }
        __syncthreads();
      }
    }
  }

  // ---- epilogue: z_q = sum of selected codes (ref order), codes, loss ----
  __syncthreads();
  double lacc = 0.0;
#pragma unroll 1
  for (int it = 0; it < 32; ++it) {
    int i = it * 256 + tid;
    int row = i >> 6, dc = i & 63;
    size_t rg = (size_t)(blk * MROWS + row);
    float4 z4 = *(const float4*)(z + rg * ND + dc * 4);
    float4 q; q.x = 0.f; q.y = 0.f; q.z = 0.f; q.w = 0.f;
    for (int l = 0; l < NL; ++l) {
      int sel = selh[row * 4 + l];
      float4 c4 = *(const float4*)(cbf + (size_t)(l * NK + sel) * ND + dc * 4);
      q.x += c4.x; q.y += c4.y; q.z += c4.z; q.w += c4.w;
    }
    *(float4*)(out + rg * ND + dc * 4) = q;
    float dx = q.x - z4.x, dy = q.y - z4.y, dz = q.z - z4.z, dw = q.w - z4.w;
    lacc += (double)dx * dx + (double)dy * dy + (double)dz * dz + (double)dw * dw;
  }
  if (tid < MROWS) {
    for (int l = 0; l < NL; ++l)
      out[(size_t)NB * ND + (size_t)(blk * MROWS + tid) * NL + l] =
          (float)selh[tid * 4 + l];
  }
  __syncthreads();
  lred[tid] = lacc;
  __syncthreads();
  if (tid == 0) {
    double s = 0.0;
    for (int t = 0; t < 256; ++t) s += lred[t];
    atomicAdd(out + (size_t)NB * ND + (size_t)NB * NL,
              (float)(s / ((double)NB * (double)ND)));
  }
}

extern "C" void kernel_launch(void* const* d_in, const int* in_sizes, int n_in,
                              void* d_out, int out_size, void* d_ws, size_t ws_size,
                              hipStream_t stream) {
  const float* z  = (const float*)d_in[0];
  const float* cb = (const float*)d_in[1];
  float* out = (float*)d_out;

  unsigned short* whi = (unsigned short*)d_ws;                 // 2 MB
  unsigned short* wlo = whi + (size_t)NL * NK * ND;            // 2 MB
  float* c2w = (float*)(wlo + (size_t)NL * NK * ND);           // 16 KB

  // zero the loss slot (harness poisons d_out with 0xAA)
  hipMemsetAsync((void*)(out + (size_t)NB * ND + (size_t)NB * NL), 0,
                 sizeof(float), stream);

  prep_split<<<dim3(4096), dim3(256), 0, stream>>>(cb, whi, wlo);
  prep_c2<<<dim3(4096), dim3(64), 0, stream>>>(cb, c2w);

  const size_t shmem = 74240;
  hipFuncSetAttribute((const void*)rvq_main,
                      hipFuncAttributeMaxDynamicSharedMemorySize, (int)shmem);
  rvq_main<<<dim3(NBLK), dim3(256), shmem, stream>>>(z, cb, whi, wlo, c2w, out);
}